// Round 1
// baseline (744.489 us; speedup 1.0000x reference)
//
#include <hip/hip_runtime.h>
#include <hip/hip_bf16.h>

#define NN 50000
#define EE 500000
#define DIN 64
#define HIDD 128
#define NG 64

struct GemmW {
  const float* W[4];
  const float* b[4];
};

// ---------------- CSR build ----------------
__global__ __launch_bounds__(256) void count_kernel(const int* __restrict__ ei,
                                                    int* __restrict__ cnt, int E) {
  int e = blockIdx.x * 256 + threadIdx.x;
  if (e < E) atomicAdd(&cnt[ei[E + e]], 1);
}

// exclusive scan over N counts; writes starts[0..N] and copies cursor back into cnts
__global__ __launch_bounds__(1024) void scan_kernel(int* __restrict__ cnts,
                                                    int* __restrict__ starts, int N) {
  __shared__ int sh[1024];
  int t = threadIdx.x;
  int carry = 0;
  for (int base = 0; base < N; base += 1024) {
    int idx = base + t;
    int v = (idx < N) ? cnts[idx] : 0;
    sh[t] = v;
    __syncthreads();
    for (int off = 1; off < 1024; off <<= 1) {
      int add = (t >= off) ? sh[t - off] : 0;
      __syncthreads();
      sh[t] += add;
      __syncthreads();
    }
    int excl = sh[t] - v + carry;
    if (idx < N) { starts[idx] = excl; cnts[idx] = excl; }
    carry += sh[1023];
    __syncthreads();
  }
  if (t == 0) starts[N] = carry;
}

__global__ __launch_bounds__(256) void scatter_kernel(const int* __restrict__ ei,
                                                      int* __restrict__ pos,
                                                      int* __restrict__ csr_src, int E) {
  int e = blockIdx.x * 256 + threadIdx.x;
  if (e < E) {
    int dst = ei[E + e];
    int p = atomicAdd(&pos[dst], 1);
    csr_src[p] = ei[e];
  }
}

// ---------------- fused Q|K|V|S GEMM ----------------
// out[n][mat*128 + c] = sum_k h[n][k]*W[mat][k][c] + b[mat][c]
// grid: (ceil(N/64), 4), block 256. K in {64,128}.
__global__ __launch_bounds__(256) void gemm_qkvs(const float* __restrict__ h, GemmW wp,
                                                 float* __restrict__ out, int K, int N) {
  __shared__ float hs[64][64];     // [node][k]  16KB
  __shared__ float wsm[64][128];   // [k][col]   32KB
  const int n0 = blockIdx.x * 64;
  const int mat = blockIdx.y;
  const float* __restrict__ W = wp.W[mat];
  const float* __restrict__ bias = wp.b[mat];
  const int t = threadIdx.x;
  const int tc = t & 31;   // 4 cols each -> 128 cols
  const int tn = t >> 5;   // 8 nodes each -> 64 nodes
  float acc[8][4] = {};
  for (int kb = 0; kb < K; kb += 64) {
    {
      int c4 = (t & 15) << 2;
      for (int rr = (t >> 4); rr < 64; rr += 16) {
        int gn = n0 + rr;
        float4 v = make_float4(0.f, 0.f, 0.f, 0.f);
        if (gn < N) v = *(const float4*)&h[(size_t)gn * K + kb + c4];
        *(float4*)&hs[rr][c4] = v;
      }
    }
    {
      int c4 = (t & 31) << 2;
      for (int kr = (t >> 5); kr < 64; kr += 8) {
        float4 v = *(const float4*)&W[(size_t)(kb + kr) * HIDD + c4];
        *(float4*)&wsm[kr][c4] = v;
      }
    }
    __syncthreads();
#pragma unroll 4
    for (int kk = 0; kk < 64; ++kk) {
      float4 wv = *(const float4*)&wsm[kk][tc << 2];
#pragma unroll
      for (int i = 0; i < 8; ++i) {
        float hv = hs[(tn << 3) + i][kk];
        acc[i][0] = fmaf(hv, wv.x, acc[i][0]);
        acc[i][1] = fmaf(hv, wv.y, acc[i][1]);
        acc[i][2] = fmaf(hv, wv.z, acc[i][2]);
        acc[i][3] = fmaf(hv, wv.w, acc[i][3]);
      }
    }
    __syncthreads();
  }
  float4 bv = *(const float4*)&bias[tc << 2];
  for (int i = 0; i < 8; ++i) {
    int gn = n0 + (tn << 3) + i;
    if (gn < N) {
      float4 o = make_float4(acc[i][0] + bv.x, acc[i][1] + bv.y,
                             acc[i][2] + bv.z, acc[i][3] + bv.w);
      *(float4*)&out[(size_t)gn * 512 + mat * HIDD + (tc << 2)] = o;
    }
  }
}

// ---------------- fused attention + beta gate + LN + GELU ----------------
// one wave (64 lanes) per node: 4 heads x 16 lanes, 2 channels/lane.
// QKVS layout per node row (512 floats): [0:128]=Q [128:256]=K [256:384]=V [384:512]=S
__global__ __launch_bounds__(256) void attn_fused(const float* __restrict__ qkvs,
    const int* __restrict__ starts, const int* __restrict__ csr_src,
    const float* __restrict__ Wbeta, const float* __restrict__ lng,
    const float* __restrict__ lnb, float* __restrict__ hout, int N) {
  int wid = (blockIdx.x * 256 + threadIdx.x) >> 6;
  if (wid >= N) return;
  int lane = threadIdx.x & 63;
  int gc = lane << 1;  // global channel pair == hd*32 + (lane&15)*2
  const float scale = 0.17677669529663687f;  // 1/sqrt(32)
  float2 qv = *(const float2*)&qkvs[(size_t)wid * 512 + gc];
  qv.x *= scale; qv.y *= scale;
  int s0 = starts[wid], s1 = starts[wid + 1];
  float m = -INFINITY, d = 0.f;
  float ax = 0.f, ay = 0.f;
  for (int i = s0; i < s1; ++i) {
    int src = csr_src[i];
    const float* base = &qkvs[(size_t)src * 512];
    float2 kv = *(const float2*)&base[128 + gc];
    float2 vv = *(const float2*)&base[256 + gc];
    float part = qv.x * kv.x + qv.y * kv.y;
    // reduce over the 16 lanes of this head
    part += __shfl_xor(part, 1);
    part += __shfl_xor(part, 2);
    part += __shfl_xor(part, 4);
    part += __shfl_xor(part, 8);
    float mn = fmaxf(m, part);
    float p = __expf(part - mn);
    float sc = __expf(m - mn);  // m=-inf on first edge -> sc=0
    d = d * sc + p;
    ax = ax * sc + p * vv.x;
    ay = ay * sc + p * vv.y;
    m = mn;
  }
  if (d > 0.f) { float inv = 1.f / d; ax *= inv; ay *= inv; }
  // beta gate: sigmoid([out, x_r, out-x_r] @ Wbeta)
  float2 sv = *(const float2*)&qkvs[(size_t)wid * 512 + 384 + gc];
  float bl = ax * Wbeta[gc] + ay * Wbeta[gc + 1]
           + sv.x * Wbeta[128 + gc] + sv.y * Wbeta[129 + gc]
           + (ax - sv.x) * Wbeta[256 + gc] + (ay - sv.y) * Wbeta[257 + gc];
  bl += __shfl_xor(bl, 1);  bl += __shfl_xor(bl, 2);  bl += __shfl_xor(bl, 4);
  bl += __shfl_xor(bl, 8);  bl += __shfl_xor(bl, 16); bl += __shfl_xor(bl, 32);
  float beta = 1.f / (1.f + __expf(-bl));
  float hx = beta * sv.x + (1.f - beta) * ax;
  float hy = beta * sv.y + (1.f - beta) * ay;
  // LayerNorm over 128 across the wave
  float s = hx + hy, sq = hx * hx + hy * hy;
  s += __shfl_xor(s, 1);  sq += __shfl_xor(sq, 1);
  s += __shfl_xor(s, 2);  sq += __shfl_xor(sq, 2);
  s += __shfl_xor(s, 4);  sq += __shfl_xor(sq, 4);
  s += __shfl_xor(s, 8);  sq += __shfl_xor(sq, 8);
  s += __shfl_xor(s, 16); sq += __shfl_xor(sq, 16);
  s += __shfl_xor(s, 32); sq += __shfl_xor(sq, 32);
  float mu = s * (1.f / 128.f);
  float var = sq * (1.f / 128.f) - mu * mu;
  float rstd = 1.f / sqrtf(var + 1e-5f);
  float y0 = (hx - mu) * rstd * lng[gc] + lnb[gc];
  float y1 = (hy - mu) * rstd * lng[gc + 1] + lnb[gc + 1];
  // exact GELU
  y0 = 0.5f * y0 * (1.f + erff(y0 * 0.70710678118654752f));
  y1 = 0.5f * y1 * (1.f + erff(y1 * 0.70710678118654752f));
  *(float2*)&hout[(size_t)wid * 128 + gc] = make_float2(y0, y1);
}

// ---------------- mean pool (stage 1: per-block LDS partials) ----------------
__global__ __launch_bounds__(256) void pool_kernel(const float* __restrict__ h,
    const int* __restrict__ batch, float* __restrict__ g,
    float* __restrict__ gcnt, int N) {
  __shared__ float accS[NG * HIDD];  // 32KB
  __shared__ float cntS[NG];
  int t = threadIdx.x;
  for (int i = t; i < NG * HIDD; i += 256) accS[i] = 0.f;
  if (t < NG) cntS[t] = 0.f;
  __syncthreads();
  int lane = t & 63, grp = t >> 6;
  for (int n = blockIdx.x * 4 + grp; n < N; n += gridDim.x * 4) {
    int b = batch[n];
    float2 hv = *(const float2*)&h[(size_t)n * HIDD + (lane << 1)];
    atomicAdd(&accS[b * HIDD + (lane << 1)], hv.x);
    atomicAdd(&accS[b * HIDD + (lane << 1) + 1], hv.y);
    if (lane == 0) atomicAdd(&cntS[b], 1.f);
  }
  __syncthreads();
  for (int i = t; i < NG * HIDD; i += 256)
    if (accS[i] != 0.f) atomicAdd(&g[i], accS[i]);
  if (t < NG && cntS[t] != 0.f) atomicAdd(&gcnt[t], cntS[t]);
}

// ---------------- final MLP (single block) ----------------
__global__ __launch_bounds__(256) void final_kernel(const float* __restrict__ g,
    const float* __restrict__ gcnt, const float* __restrict__ W1,
    const float* __restrict__ b1, const float* __restrict__ W2,
    const float* __restrict__ b2, float* __restrict__ out) {
  __shared__ float gS[NG * HIDD];
  __shared__ float hmS[NG * HIDD];
  int t = threadIdx.x;
  for (int i = t; i < NG * HIDD; i += 256) {
    int gr = i >> 7;
    gS[i] = g[i] / fmaxf(gcnt[gr], 1.f);
  }
  __syncthreads();
  for (int i = t; i < NG * HIDD; i += 256) {
    int gr = i >> 7, col = i & 127;
    float s = b1[col];
    for (int k = 0; k < HIDD; ++k) s = fmaf(gS[gr * HIDD + k], W1[k * HIDD + col], s);
    hmS[i] = 0.5f * s * (1.f + erff(s * 0.70710678118654752f));
  }
  __syncthreads();
  if (t < NG) {
    float s = b2[0];
    for (int k = 0; k < HIDD; ++k) s = fmaf(hmS[t * HIDD + k], W2[k], s);
    out[t] = s;
  }
}

extern "C" void kernel_launch(void* const* d_in, const int* in_sizes, int n_in,
                              void* d_out, int out_size, void* d_ws, size_t ws_size,
                              hipStream_t stream) {
  const float* x        = (const float*)d_in[0];
  const int*   ei       = (const int*)d_in[1];
  const int*   batch    = (const int*)d_in[2];
  const float* l0_Wq    = (const float*)d_in[3];
  const float* l0_bq    = (const float*)d_in[4];
  const float* l0_Wk    = (const float*)d_in[5];
  const float* l0_bk    = (const float*)d_in[6];
  const float* l0_Wv    = (const float*)d_in[7];
  const float* l0_bv    = (const float*)d_in[8];
  const float* l0_Ws    = (const float*)d_in[9];
  const float* l0_bs    = (const float*)d_in[10];
  const float* l0_Wbeta = (const float*)d_in[11];
  const float* l0_lng   = (const float*)d_in[12];
  const float* l0_lnb   = (const float*)d_in[13];
  const float* Wq       = (const float*)d_in[14];
  const float* bq       = (const float*)d_in[15];
  const float* Wk       = (const float*)d_in[16];
  const float* bk       = (const float*)d_in[17];
  const float* Wv       = (const float*)d_in[18];
  const float* bv       = (const float*)d_in[19];
  const float* Ws       = (const float*)d_in[20];
  const float* bs       = (const float*)d_in[21];
  const float* Wbeta    = (const float*)d_in[22];
  const float* lng      = (const float*)d_in[23];
  const float* lnb      = (const float*)d_in[24];
  const float* mlp_W1   = (const float*)d_in[25];
  const float* mlp_b1   = (const float*)d_in[26];
  const float* mlp_W2   = (const float*)d_in[27];
  const float* mlp_b2   = (const float*)d_in[28];
  float* outp = (float*)d_out;

  char* ws = (char*)d_ws;
  size_t off = 0;
  auto alloc = [&](size_t bytes) -> void* {
    void* p = ws + off;
    off = (off + bytes + 255) & ~(size_t)255;
    return p;
  };
  float* h0     = (float*)alloc((size_t)NN * HIDD * 4);
  float* h1     = (float*)alloc((size_t)NN * HIDD * 4);
  float* qkvs   = (float*)alloc((size_t)NN * 512 * 4);
  int*   starts = (int*)alloc((size_t)(NN + 1) * 4);
  int*   pos    = (int*)alloc((size_t)NN * 4);
  int*   csr    = (int*)alloc((size_t)EE * 4);
  float* g      = (float*)alloc((size_t)NG * HIDD * 4);
  float* gcnt   = (float*)alloc((size_t)NG * 4);
  (void)ws_size; (void)in_sizes; (void)n_in; (void)out_size;

  // ---- CSR build (by dst) ----
  hipMemsetAsync(pos, 0, (size_t)NN * 4, stream);
  count_kernel<<<(EE + 255) / 256, 256, 0, stream>>>(ei, pos, EE);
  scan_kernel<<<1, 1024, 0, stream>>>(pos, starts, NN);
  scatter_kernel<<<(EE + 255) / 256, 256, 0, stream>>>(ei, pos, csr, EE);

  dim3 ggrid((NN + 63) / 64, 4);
  int agrid = NN / 4;  // one wave per node, 4 waves per block

  // ---- layer 0 (64 -> 128) ----
  GemmW w0 = {{l0_Wq, l0_Wk, l0_Wv, l0_Ws}, {l0_bq, l0_bk, l0_bv, l0_bs}};
  gemm_qkvs<<<ggrid, 256, 0, stream>>>(x, w0, qkvs, DIN, NN);
  attn_fused<<<agrid, 256, 0, stream>>>(qkvs, starts, csr, l0_Wbeta, l0_lng, l0_lnb, h0, NN);

  // ---- layer 1 ----
  GemmW w1 = {{Wq, Wk, Wv, Ws}, {bq, bk, bv, bs}};
  gemm_qkvs<<<ggrid, 256, 0, stream>>>(h0, w1, qkvs, HIDD, NN);
  attn_fused<<<agrid, 256, 0, stream>>>(qkvs, starts, csr, Wbeta, lng, lnb, h1, NN);

  // ---- layer 2 ----
  const size_t wO = (size_t)HIDD * HIDD;
  GemmW w2 = {{Wq + wO, Wk + wO, Wv + wO, Ws + wO},
              {bq + HIDD, bk + HIDD, bv + HIDD, bs + HIDD}};
  gemm_qkvs<<<ggrid, 256, 0, stream>>>(h1, w2, qkvs, HIDD, NN);
  attn_fused<<<agrid, 256, 0, stream>>>(qkvs, starts, csr, Wbeta + 3 * HIDD,
                                        lng + HIDD, lnb + HIDD, h0, NN);

  // ---- pool + MLP ----
  hipMemsetAsync(g, 0, (size_t)NG * HIDD * 4, stream);
  hipMemsetAsync(gcnt, 0, (size_t)NG * 4, stream);
  pool_kernel<<<256, 256, 0, stream>>>(h0, batch, g, gcnt, NN);
  final_kernel<<<1, 256, 0, stream>>>(g, gcnt, mlp_W1, mlp_b1, mlp_W2, mlp_b2, outp);
}

// Round 2
// 540.196 us; speedup vs baseline: 1.3782x; 1.3782x over previous
//
#include <hip/hip_runtime.h>
#include <hip/hip_bf16.h>

#define NN 50000
#define EE 500000
#define DIN 64
#define HIDD 128
#define NG 64
#define NB1 49  // ceil(NN/1024) scan blocks

typedef short short8 __attribute__((ext_vector_type(8)));
typedef float f32x4 __attribute__((ext_vector_type(4)));

__device__ __forceinline__ short f2bf(float f) {
  unsigned u = __float_as_uint(f);
  u += 0x7fffu + ((u >> 16) & 1u);  // RNE
  return (short)(u >> 16);
}

struct BiasW { const float* b[4]; };
struct PrepW { const float* w[12]; };

// ---------------- CSR build ----------------
__global__ __launch_bounds__(256) void count_kernel(const int* __restrict__ ei,
                                                    int* __restrict__ cnt, int E) {
  int e = blockIdx.x * 256 + threadIdx.x;
  if (e < E) atomicAdd(&cnt[ei[E + e]], 1);
}

__global__ __launch_bounds__(1024) void scan1_kernel(const int* __restrict__ cnts,
                                                     int* __restrict__ starts,
                                                     int* __restrict__ btot) {
  __shared__ int sh[1024];
  int t = threadIdx.x;
  int idx = blockIdx.x * 1024 + t;
  int v = (idx < NN) ? cnts[idx] : 0;
  sh[t] = v;
  __syncthreads();
  for (int off = 1; off < 1024; off <<= 1) {
    int add = (t >= off) ? sh[t - off] : 0;
    __syncthreads();
    sh[t] += add;
    __syncthreads();
  }
  if (idx < NN) starts[idx] = sh[t] - v;
  if (t == 1023) btot[blockIdx.x] = sh[1023];
}

__global__ __launch_bounds__(64) void scan2_kernel(const int* __restrict__ btot,
                                                   int* __restrict__ boff,
                                                   int* __restrict__ starts) {
  int t = threadIdx.x;
  int orig = (t < NB1) ? btot[t] : 0;
  int v = orig;
  for (int off = 1; off < 64; off <<= 1) {
    int n_ = __shfl_up(v, off);
    if (t >= off) v += n_;
  }
  if (t < NB1) boff[t] = v - orig;
  if (t == NB1 - 1) starts[NN] = v;
}

__global__ __launch_bounds__(256) void scan3_kernel(int* __restrict__ starts,
                                                    const int* __restrict__ boff,
                                                    int* __restrict__ pos) {
  int i = blockIdx.x * 256 + threadIdx.x;
  if (i < NN) {
    int s = starts[i] + boff[i >> 10];
    starts[i] = s;
    pos[i] = s;
  }
}

__global__ __launch_bounds__(256) void scatter_kernel(const int* __restrict__ ei,
                                                      int* __restrict__ pos,
                                                      int* __restrict__ csr_src, int E) {
  int e = blockIdx.x * 256 + threadIdx.x;
  if (e < E) {
    int dst = ei[E + e];
    int p = atomicAdd(&pos[dst], 1);
    csr_src[p] = ei[e];
  }
}

// ---------------- weight prep: transpose + cast to bf16 ----------------
// wT layout: mats 0..3 (l0, K=64): [128][64] at m*8192
//            mats 4..11 (layers, K=128): [128][128] at 32768+(m-4)*16384
__global__ __launch_bounds__(256) void prep_kernel(PrepW pw, short* __restrict__ wT) {
  int o = blockIdx.x * 256 + threadIdx.x;
  if (o >= 163840) return;
  int m, local, K;
  if (o < 32768) { m = o >> 13; local = o & 8191; K = 64; }
  else { int oo = o - 32768; m = 4 + (oo >> 14); local = oo & 16383; K = 128; }
  int n = (K == 64) ? (local >> 6) : (local >> 7);
  int k = local & (K - 1);
  wT[o] = f2bf(pw.w[m][(size_t)k * 128 + n]);
}

// ---------------- bf16 MFMA GEMM: h[N,K] x W[K,128] (x4 mats) ----------------
// grid: (ceil(N/64), 4), block 256 (4 waves, 16 rows each).
// mat 0 -> Q (f32), 1 -> K (bf16 kv[:,0:128]), 2 -> V (bf16 kv[:,128:256]), 3 -> S (f32)
template <int K>
__global__ __launch_bounds__(256) void gemm_qkvs(
    const float* __restrict__ h, const short* __restrict__ wT, BiasW bw,
    float* __restrict__ qf, unsigned short* __restrict__ kvb,
    float* __restrict__ sf, int N) {
  __shared__ short aS[64 * K];
  const int n0 = blockIdx.x * 64;
  const int mat = blockIdx.y;
  const short* __restrict__ w = wT + (size_t)mat * 128 * K;
  const int t = threadIdx.x;

  // stage A tile: f32 -> bf16, XOR-swizzled rows (256B or 128B)
  const int CH = K / 8;
  for (int idx = t; idx < 64 * CH; idx += 256) {
    int row = idx / CH, slot = idx % CH;
    int gr = n0 + row;
    float4 f0 = make_float4(0.f, 0.f, 0.f, 0.f), f1 = f0;
    if (gr < N) {
      const float* hp = &h[(size_t)gr * K + slot * 8];
      f0 = *(const float4*)hp;
      f1 = *(const float4*)(hp + 4);
    }
    short8 pk;
    pk[0] = f2bf(f0.x); pk[1] = f2bf(f0.y); pk[2] = f2bf(f0.z); pk[3] = f2bf(f0.w);
    pk[4] = f2bf(f1.x); pk[5] = f2bf(f1.y); pk[6] = f2bf(f1.z); pk[7] = f2bf(f1.w);
    unsigned byte = row * (2 * K) + ((slot * 16) ^ ((row & 7) << 4));
    *(short8*)((char*)aS + byte) = pk;
  }
  __syncthreads();

  const int l = t & 63, w4 = t >> 6;
  const int lr = l & 15, lk = l >> 4;
  const int arow = w4 * 16 + lr;
  f32x4 acc[8] = {};
#pragma unroll
  for (int ks = 0; ks < K / 32; ++ks) {
    unsigned abyte = arow * (2 * K) + ((((ks * 4 + lk) * 16)) ^ ((arow & 7) << 4));
    short8 a = *(const short8*)((const char*)aS + abyte);
#pragma unroll
    for (int cf = 0; cf < 8; ++cf) {
      short8 b = *(const short8*)&w[(size_t)(cf * 16 + lr) * K + ks * 32 + lk * 8];
      acc[cf] = __builtin_amdgcn_mfma_f32_16x16x32_bf16(a, b, acc[cf], 0, 0, 0);
    }
  }

  const float* __restrict__ bias = bw.b[mat];
#pragma unroll
  for (int cf = 0; cf < 8; ++cf) {
    int col = cf * 16 + lr;
    float bv = bias[col];
#pragma unroll
    for (int r = 0; r < 4; ++r) {
      int row = n0 + w4 * 16 + lk * 4 + r;
      if (row < N) {
        float val = acc[cf][r] + bv;
        if (mat == 0) qf[(size_t)row * 128 + col] = val;
        else if (mat == 3) sf[(size_t)row * 128 + col] = val;
        else kvb[(size_t)row * 256 + (mat == 2 ? 128 : 0) + col] = (unsigned short)f2bf(val);
      }
    }
  }
}

// ---------------- fused attention + beta gate + LN + GELU ----------------
// one wave per node: 4 heads x 16 lanes, 2 channels/lane. K/V gathered as bf16.
__global__ __launch_bounds__(256) void attn_fused(
    const float* __restrict__ qf, const unsigned* __restrict__ kvu,
    const float* __restrict__ sf, const int* __restrict__ starts,
    const int* __restrict__ csr, const float* __restrict__ Wbeta,
    const float* __restrict__ lng, const float* __restrict__ lnb,
    float* __restrict__ hout, int N) {
  int wid = (blockIdx.x * 256 + threadIdx.x) >> 6;
  if (wid >= N) return;
  int lane = threadIdx.x & 63;
  int gc = lane << 1;
  const float scale = 0.17677669529663687f;  // 1/sqrt(32)
  float2 qv = *(const float2*)&qf[(size_t)wid * 128 + gc];
  float qx = qv.x * scale, qy = qv.y * scale;
  int s0 = starts[wid], s1 = starts[wid + 1];
  float m = -INFINITY, d = 0.f, ax = 0.f, ay = 0.f;
  int i = s0;
  for (; i + 1 < s1; i += 2) {
    int sA = csr[i], sB = csr[i + 1];
    unsigned kA = kvu[(size_t)sA * 128 + lane];
    unsigned vA = kvu[(size_t)sA * 128 + 64 + lane];
    unsigned kB = kvu[(size_t)sB * 128 + lane];
    unsigned vB = kvu[(size_t)sB * 128 + 64 + lane];
    {
      float kx = __uint_as_float(kA << 16), ky = __uint_as_float(kA & 0xffff0000u);
      float part = qx * kx + qy * ky;
      part += __shfl_xor(part, 1); part += __shfl_xor(part, 2);
      part += __shfl_xor(part, 4); part += __shfl_xor(part, 8);
      float mn = fmaxf(m, part);
      float p = __expf(part - mn), sc = __expf(m - mn);
      float vx = __uint_as_float(vA << 16), vy = __uint_as_float(vA & 0xffff0000u);
      d = d * sc + p; ax = ax * sc + p * vx; ay = ay * sc + p * vy; m = mn;
    }
    {
      float kx = __uint_as_float(kB << 16), ky = __uint_as_float(kB & 0xffff0000u);
      float part = qx * kx + qy * ky;
      part += __shfl_xor(part, 1); part += __shfl_xor(part, 2);
      part += __shfl_xor(part, 4); part += __shfl_xor(part, 8);
      float mn = fmaxf(m, part);
      float p = __expf(part - mn), sc = __expf(m - mn);
      float vx = __uint_as_float(vB << 16), vy = __uint_as_float(vB & 0xffff0000u);
      d = d * sc + p; ax = ax * sc + p * vx; ay = ay * sc + p * vy; m = mn;
    }
  }
  if (i < s1) {
    int sA = csr[i];
    unsigned kA = kvu[(size_t)sA * 128 + lane];
    unsigned vA = kvu[(size_t)sA * 128 + 64 + lane];
    float kx = __uint_as_float(kA << 16), ky = __uint_as_float(kA & 0xffff0000u);
    float part = qx * kx + qy * ky;
    part += __shfl_xor(part, 1); part += __shfl_xor(part, 2);
    part += __shfl_xor(part, 4); part += __shfl_xor(part, 8);
    float mn = fmaxf(m, part);
    float p = __expf(part - mn), sc = __expf(m - mn);
    float vx = __uint_as_float(vA << 16), vy = __uint_as_float(vA & 0xffff0000u);
    d = d * sc + p; ax = ax * sc + p * vx; ay = ay * sc + p * vy; m = mn;
  }
  if (d > 0.f) { float inv = 1.f / d; ax *= inv; ay *= inv; }
  float2 sv = *(const float2*)&sf[(size_t)wid * 128 + gc];
  float bl = ax * Wbeta[gc] + ay * Wbeta[gc + 1]
           + sv.x * Wbeta[128 + gc] + sv.y * Wbeta[129 + gc]
           + (ax - sv.x) * Wbeta[256 + gc] + (ay - sv.y) * Wbeta[257 + gc];
  bl += __shfl_xor(bl, 1);  bl += __shfl_xor(bl, 2);  bl += __shfl_xor(bl, 4);
  bl += __shfl_xor(bl, 8);  bl += __shfl_xor(bl, 16); bl += __shfl_xor(bl, 32);
  float beta = 1.f / (1.f + __expf(-bl));
  float hx = beta * sv.x + (1.f - beta) * ax;
  float hy = beta * sv.y + (1.f - beta) * ay;
  float s = hx + hy, sq = hx * hx + hy * hy;
  s += __shfl_xor(s, 1);  sq += __shfl_xor(sq, 1);
  s += __shfl_xor(s, 2);  sq += __shfl_xor(sq, 2);
  s += __shfl_xor(s, 4);  sq += __shfl_xor(sq, 4);
  s += __shfl_xor(s, 8);  sq += __shfl_xor(sq, 8);
  s += __shfl_xor(s, 16); sq += __shfl_xor(sq, 16);
  s += __shfl_xor(s, 32); sq += __shfl_xor(sq, 32);
  float mu = s * (1.f / 128.f);
  float var = sq * (1.f / 128.f) - mu * mu;
  float rstd = 1.f / sqrtf(var + 1e-5f);
  float y0 = (hx - mu) * rstd * lng[gc] + lnb[gc];
  float y1 = (hy - mu) * rstd * lng[gc + 1] + lnb[gc + 1];
  y0 = 0.5f * y0 * (1.f + erff(y0 * 0.70710678118654752f));
  y1 = 0.5f * y1 * (1.f + erff(y1 * 0.70710678118654752f));
  *(float2*)&hout[(size_t)wid * 128 + gc] = make_float2(y0, y1);
}

// ---------------- mean pool ----------------
__global__ __launch_bounds__(256) void pool_kernel(const float* __restrict__ h,
    const int* __restrict__ batch, float* __restrict__ g,
    float* __restrict__ gcnt, int N) {
  __shared__ float accS[NG * HIDD];
  __shared__ float cntS[NG];
  int t = threadIdx.x;
  for (int i = t; i < NG * HIDD; i += 256) accS[i] = 0.f;
  if (t < NG) cntS[t] = 0.f;
  __syncthreads();
  int lane = t & 63, grp = t >> 6;
  for (int n = blockIdx.x * 4 + grp; n < N; n += gridDim.x * 4) {
    int b = batch[n];
    float2 hv = *(const float2*)&h[(size_t)n * HIDD + (lane << 1)];
    atomicAdd(&accS[b * HIDD + (lane << 1)], hv.x);
    atomicAdd(&accS[b * HIDD + (lane << 1) + 1], hv.y);
    if (lane == 0) atomicAdd(&cntS[b], 1.f);
  }
  __syncthreads();
  for (int i = t; i < NG * HIDD; i += 256)
    if (accS[i] != 0.f) atomicAdd(&g[i], accS[i]);
  if (t < NG && cntS[t] != 0.f) atomicAdd(&gcnt[t], cntS[t]);
}

// ---------------- final MLP (single block) ----------------
__global__ __launch_bounds__(256) void final_kernel(const float* __restrict__ g,
    const float* __restrict__ gcnt, const float* __restrict__ W1,
    const float* __restrict__ b1, const float* __restrict__ W2,
    const float* __restrict__ b2, float* __restrict__ out) {
  __shared__ float gS[NG * HIDD];
  __shared__ float hmS[NG * HIDD];
  int t = threadIdx.x;
  for (int i = t; i < NG * HIDD; i += 256) {
    int gr = i >> 7;
    gS[i] = g[i] / fmaxf(gcnt[gr], 1.f);
  }
  __syncthreads();
  for (int i = t; i < NG * HIDD; i += 256) {
    int gr = i >> 7, col = i & 127;
    float s = b1[col];
    for (int k = 0; k < HIDD; ++k) s = fmaf(gS[gr * HIDD + k], W1[k * HIDD + col], s);
    hmS[i] = 0.5f * s * (1.f + erff(s * 0.70710678118654752f));
  }
  __syncthreads();
  if (t < NG) {
    float s = b2[0];
    for (int k = 0; k < HIDD; ++k) s = fmaf(hmS[t * HIDD + k], W2[k], s);
    out[t] = s;
  }
}

extern "C" void kernel_launch(void* const* d_in, const int* in_sizes, int n_in,
                              void* d_out, int out_size, void* d_ws, size_t ws_size,
                              hipStream_t stream) {
  const float* x        = (const float*)d_in[0];
  const int*   ei       = (const int*)d_in[1];
  const int*   batch    = (const int*)d_in[2];
  const float* l0_Wq    = (const float*)d_in[3];
  const float* l0_bq    = (const float*)d_in[4];
  const float* l0_Wk    = (const float*)d_in[5];
  const float* l0_bk    = (const float*)d_in[6];
  const float* l0_Wv    = (const float*)d_in[7];
  const float* l0_bv    = (const float*)d_in[8];
  const float* l0_Ws    = (const float*)d_in[9];
  const float* l0_bs    = (const float*)d_in[10];
  const float* l0_Wbeta = (const float*)d_in[11];
  const float* l0_lng   = (const float*)d_in[12];
  const float* l0_lnb   = (const float*)d_in[13];
  const float* Wq       = (const float*)d_in[14];
  const float* bq       = (const float*)d_in[15];
  const float* Wk       = (const float*)d_in[16];
  const float* bk       = (const float*)d_in[17];
  const float* Wv       = (const float*)d_in[18];
  const float* bv       = (const float*)d_in[19];
  const float* Ws       = (const float*)d_in[20];
  const float* bs       = (const float*)d_in[21];
  const float* Wbeta    = (const float*)d_in[22];
  const float* lng      = (const float*)d_in[23];
  const float* lnb      = (const float*)d_in[24];
  const float* mlp_W1   = (const float*)d_in[25];
  const float* mlp_b1   = (const float*)d_in[26];
  const float* mlp_W2   = (const float*)d_in[27];
  const float* mlp_b2   = (const float*)d_in[28];
  float* outp = (float*)d_out;

  char* ws = (char*)d_ws;
  size_t off = 0;
  auto alloc = [&](size_t bytes) -> void* {
    void* p = ws + off;
    off = (off + bytes + 255) & ~(size_t)255;
    return p;
  };
  float*  h0     = (float*)alloc((size_t)NN * HIDD * 4);
  float*  h1     = (float*)alloc((size_t)NN * HIDD * 4);
  float*  qf     = (float*)alloc((size_t)NN * HIDD * 4);
  float*  sf     = (float*)alloc((size_t)NN * HIDD * 4);
  unsigned short* kvb = (unsigned short*)alloc((size_t)NN * 256 * 2);
  short*  wT     = (short*)alloc((size_t)163840 * 2);
  int*    starts = (int*)alloc((size_t)(NN + 1) * 4);
  int*    pos    = (int*)alloc((size_t)NN * 4);
  int*    csr    = (int*)alloc((size_t)EE * 4);
  int*    btot   = (int*)alloc((size_t)NB1 * 4);
  int*    boff   = (int*)alloc((size_t)NB1 * 4);
  float*  g      = (float*)alloc((size_t)NG * HIDD * 4);
  float*  gcnt   = (float*)alloc((size_t)NG * 4);
  (void)ws_size; (void)in_sizes; (void)n_in; (void)out_size;

  // ---- weight prep (transpose + bf16 cast) ----
  PrepW pw = {{l0_Wq, l0_Wk, l0_Wv, l0_Ws,
               Wq, Wk, Wv, Ws,
               Wq + 16384, Wk + 16384, Wv + 16384, Ws + 16384}};
  prep_kernel<<<640, 256, 0, stream>>>(pw, wT);

  // ---- CSR build (by dst) ----
  hipMemsetAsync(pos, 0, (size_t)NN * 4, stream);
  count_kernel<<<(EE + 255) / 256, 256, 0, stream>>>(ei, pos, EE);
  scan1_kernel<<<NB1, 1024, 0, stream>>>(pos, starts, btot);
  scan2_kernel<<<1, 64, 0, stream>>>(btot, boff, starts);
  scan3_kernel<<<(NN + 255) / 256, 256, 0, stream>>>(starts, boff, pos);
  scatter_kernel<<<(EE + 255) / 256, 256, 0, stream>>>(ei, pos, csr, EE);

  dim3 ggrid((NN + 63) / 64, 4);
  int agrid = (NN + 3) / 4;
  const unsigned* kvu = (const unsigned*)kvb;

  // ---- layer 0 (64 -> 128) ----
  BiasW b0 = {{l0_bq, l0_bk, l0_bv, l0_bs}};
  gemm_qkvs<DIN><<<ggrid, 256, 0, stream>>>(x, wT, b0, qf, kvb, sf, NN);
  attn_fused<<<agrid, 256, 0, stream>>>(qf, kvu, sf, starts, csr, l0_Wbeta,
                                        l0_lng, l0_lnb, h0, NN);

  // ---- layer 1 ----
  BiasW b1s = {{bq, bk, bv, bs}};
  gemm_qkvs<HIDD><<<ggrid, 256, 0, stream>>>(h0, wT + 32768, b1s, qf, kvb, sf, NN);
  attn_fused<<<agrid, 256, 0, stream>>>(qf, kvu, sf, starts, csr, Wbeta,
                                        lng, lnb, h1, NN);

  // ---- layer 2 ----
  BiasW b2s = {{bq + HIDD, bk + HIDD, bv + HIDD, bs + HIDD}};
  gemm_qkvs<HIDD><<<ggrid, 256, 0, stream>>>(h1, wT + 98304, b2s, qf, kvb, sf, NN);
  attn_fused<<<agrid, 256, 0, stream>>>(qf, kvu, sf, starts, csr, Wbeta + 384,
                                        lng + HIDD, lnb + HIDD, h0, NN);

  // ---- pool + MLP ----
  hipMemsetAsync(g, 0, (size_t)NG * HIDD * 4, stream);
  hipMemsetAsync(gcnt, 0, (size_t)NG * 4, stream);
  pool_kernel<<<256, 256, 0, stream>>>(h0, batch, g, gcnt, NN);
  final_kernel<<<1, 256, 0, stream>>>(g, gcnt, mlp_W1, mlp_b1, mlp_W2, mlp_b2, outp);
}

// Round 3
// 515.659 us; speedup vs baseline: 1.4438x; 1.0476x over previous
//
#include <hip/hip_runtime.h>
#include <hip/hip_bf16.h>

#define NN 50000
#define EE 500000
#define DIN 64
#define HIDD 128
#define NG 64
#define NB1 49  // ceil(NN/1024) scan blocks

typedef short short8 __attribute__((ext_vector_type(8)));
typedef float f32x4 __attribute__((ext_vector_type(4)));

__device__ __forceinline__ short f2bf(float f) {
  unsigned u = __float_as_uint(f);
  u += 0x7fffu + ((u >> 16) & 1u);  // RNE
  return (short)(u >> 16);
}

struct BiasW { const float* b[4]; };
struct PrepW { const float* w[12]; };

// ---------------- CSR build ----------------
__global__ __launch_bounds__(256) void count_kernel(const int* __restrict__ ei,
                                                    int* __restrict__ cnt, int E) {
  int e = blockIdx.x * 256 + threadIdx.x;
  if (e < E) atomicAdd(&cnt[ei[E + e]], 1);
}

__global__ __launch_bounds__(1024) void scan1_kernel(const int* __restrict__ cnts,
                                                     int* __restrict__ starts,
                                                     int* __restrict__ btot) {
  __shared__ int sh[1024];
  int t = threadIdx.x;
  int idx = blockIdx.x * 1024 + t;
  int v = (idx < NN) ? cnts[idx] : 0;
  sh[t] = v;
  __syncthreads();
  for (int off = 1; off < 1024; off <<= 1) {
    int add = (t >= off) ? sh[t - off] : 0;
    __syncthreads();
    sh[t] += add;
    __syncthreads();
  }
  if (idx < NN) starts[idx] = sh[t] - v;
  if (t == 1023) btot[blockIdx.x] = sh[1023];
}

__global__ __launch_bounds__(64) void scan2_kernel(const int* __restrict__ btot,
                                                   int* __restrict__ boff,
                                                   int* __restrict__ starts) {
  int t = threadIdx.x;
  int orig = (t < NB1) ? btot[t] : 0;
  int v = orig;
  for (int off = 1; off < 64; off <<= 1) {
    int n_ = __shfl_up(v, off);
    if (t >= off) v += n_;
  }
  if (t < NB1) boff[t] = v - orig;
  if (t == NB1 - 1) starts[NN] = v;
}

__global__ __launch_bounds__(256) void scan3_kernel(int* __restrict__ starts,
                                                    const int* __restrict__ boff,
                                                    int* __restrict__ pos) {
  int i = blockIdx.x * 256 + threadIdx.x;
  if (i < NN) {
    int s = starts[i] + boff[i >> 10];
    starts[i] = s;
    pos[i] = s;
  }
}

__global__ __launch_bounds__(256) void scatter_kernel(const int* __restrict__ ei,
                                                      int* __restrict__ pos,
                                                      int* __restrict__ csr_src, int E) {
  int e = blockIdx.x * 256 + threadIdx.x;
  if (e < E) {
    int dst = ei[E + e];
    int p = atomicAdd(&pos[dst], 1);
    csr_src[p] = ei[e];
  }
}

// ---------------- weight prep: transpose + cast to bf16 ----------------
// wT layout: mats 0..3 (l0, K=64): [128][64] at m*8192
//            mats 4..11 (layers, K=128): [128][128] at 32768+(m-4)*16384
__global__ __launch_bounds__(256) void prep_kernel(PrepW pw, short* __restrict__ wT) {
  int o = blockIdx.x * 256 + threadIdx.x;
  if (o >= 163840) return;
  int m, local, K;
  if (o < 32768) { m = o >> 13; local = o & 8191; K = 64; }
  else { int oo = o - 32768; m = 4 + (oo >> 14); local = oo & 16383; K = 128; }
  int n = (K == 64) ? (local >> 6) : (local >> 7);
  int k = local & (K - 1);
  wT[o] = f2bf(pw.w[m][(size_t)k * 128 + n]);
}

// ---------------- bf16 MFMA GEMM: h[N,K] x W[K,128], all 4 mats fused ----------------
// grid ceil(N/64), block 256 (4 waves x 16 rows). A staged once, B from L2.
// mat 0 -> Q (f32), 1 -> K (bf16 kv[:,0:128]), 2 -> V (bf16 kv[:,128:256]), 3 -> S (f32)
template <int K>
__global__ __launch_bounds__(256) void gemm_qkvs(
    const float* __restrict__ h, const short* __restrict__ wT, BiasW bw,
    float* __restrict__ qf, unsigned short* __restrict__ kvb,
    float* __restrict__ sf, int N) {
  __shared__ short aS[64 * K];
  const int n0 = blockIdx.x * 64;
  const int t = threadIdx.x;

  // stage A tile: f32 -> bf16, XOR-swizzled rows
  const int CH = K / 8;
  for (int idx = t; idx < 64 * CH; idx += 256) {
    int row = idx / CH, slot = idx % CH;
    int gr = n0 + row;
    float4 f0 = make_float4(0.f, 0.f, 0.f, 0.f), f1 = f0;
    if (gr < N) {
      const float* hp = &h[(size_t)gr * K + slot * 8];
      f0 = *(const float4*)hp;
      f1 = *(const float4*)(hp + 4);
    }
    short8 pk;
    pk[0] = f2bf(f0.x); pk[1] = f2bf(f0.y); pk[2] = f2bf(f0.z); pk[3] = f2bf(f0.w);
    pk[4] = f2bf(f1.x); pk[5] = f2bf(f1.y); pk[6] = f2bf(f1.z); pk[7] = f2bf(f1.w);
    unsigned byte = row * (2 * K) + ((slot * 16) ^ ((row & 7) << 4));
    *(short8*)((char*)aS + byte) = pk;
  }
  __syncthreads();

  const int l = t & 63, wv = t >> 6;
  const int lr = l & 15, lk = l >> 4;
  const int arow = wv * 16 + lr;

  // A-fragments once into registers
  short8 afrag[K / 32];
#pragma unroll
  for (int ks = 0; ks < K / 32; ++ks) {
    unsigned abyte = arow * (2 * K) + ((((ks * 4 + lk) * 16)) ^ ((arow & 7) << 4));
    afrag[ks] = *(const short8*)((const char*)aS + abyte);
  }

#pragma unroll
  for (int mat = 0; mat < 4; ++mat) {
    const short* __restrict__ w = wT + (size_t)mat * 128 * K;
    f32x4 acc[8] = {};
#pragma unroll
    for (int ks = 0; ks < K / 32; ++ks) {
#pragma unroll
      for (int cf = 0; cf < 8; ++cf) {
        short8 b = *(const short8*)&w[(size_t)(cf * 16 + lr) * K + ks * 32 + lk * 8];
        acc[cf] = __builtin_amdgcn_mfma_f32_16x16x32_bf16(afrag[ks], b, acc[cf], 0, 0, 0);
      }
    }
    const float* __restrict__ bias = bw.b[mat];
#pragma unroll
    for (int cf = 0; cf < 8; ++cf) {
      int col = cf * 16 + lr;
      float bv = bias[col];
#pragma unroll
      for (int r = 0; r < 4; ++r) {
        int row = n0 + wv * 16 + lk * 4 + r;
        if (row < N) {
          float val = acc[cf][r] + bv;
          if (mat == 0) qf[(size_t)row * 128 + col] = val;
          else if (mat == 3) sf[(size_t)row * 128 + col] = val;
          else kvb[(size_t)row * 256 + (mat == 2 ? 128 : 0) + col] = (unsigned short)f2bf(val);
        }
      }
    }
  }
}

// ---------------- fused attention + beta gate + LN + GELU ----------------
// one wave per node: 4 heads x 16 lanes, 2 channels/lane. bf16 K/V gather.
// No running-max: p = exp(alpha) directly (|alpha| << 88, mathematically identical).
__device__ __forceinline__ void att_upd(unsigned kw, unsigned vw, float qx, float qy,
                                        float& d, float& ax, float& ay) {
  float kx = __uint_as_float(kw << 16), ky = __uint_as_float(kw & 0xffff0000u);
  float part = qx * kx + qy * ky;
  part += __shfl_xor(part, 1); part += __shfl_xor(part, 2);
  part += __shfl_xor(part, 4); part += __shfl_xor(part, 8);
  float p = __expf(part);
  float vx = __uint_as_float(vw << 16), vy = __uint_as_float(vw & 0xffff0000u);
  d += p; ax = fmaf(p, vx, ax); ay = fmaf(p, vy, ay);
}

__global__ __launch_bounds__(256) void attn_fused(
    const float* __restrict__ qf, const unsigned* __restrict__ kvu,
    const float* __restrict__ sf, const int* __restrict__ starts,
    const int* __restrict__ csr, const float* __restrict__ Wbeta,
    const float* __restrict__ lng, const float* __restrict__ lnb,
    float* __restrict__ hout, int N) {
  int wid = (blockIdx.x * 256 + threadIdx.x) >> 6;
  if (wid >= N) return;
  int lane = threadIdx.x & 63;
  int gc = lane << 1;
  const float scale = 0.17677669529663687f;  // 1/sqrt(32)
  float2 qv = *(const float2*)&qf[(size_t)wid * 128 + gc];
  float qx = qv.x * scale, qy = qv.y * scale;
  int s0 = starts[wid], s1 = starts[wid + 1];
  float d = 0.f, ax = 0.f, ay = 0.f;
  int i = s0;
  for (; i + 3 < s1; i += 4) {
    int sA = csr[i], sB = csr[i + 1], sC = csr[i + 2], sD = csr[i + 3];
    unsigned kA = kvu[(size_t)sA * 128 + lane];
    unsigned vA = kvu[(size_t)sA * 128 + 64 + lane];
    unsigned kB = kvu[(size_t)sB * 128 + lane];
    unsigned vB = kvu[(size_t)sB * 128 + 64 + lane];
    unsigned kC = kvu[(size_t)sC * 128 + lane];
    unsigned vC = kvu[(size_t)sC * 128 + 64 + lane];
    unsigned kD = kvu[(size_t)sD * 128 + lane];
    unsigned vD = kvu[(size_t)sD * 128 + 64 + lane];
    att_upd(kA, vA, qx, qy, d, ax, ay);
    att_upd(kB, vB, qx, qy, d, ax, ay);
    att_upd(kC, vC, qx, qy, d, ax, ay);
    att_upd(kD, vD, qx, qy, d, ax, ay);
  }
  if (i + 1 < s1) {
    int sA = csr[i], sB = csr[i + 1];
    unsigned kA = kvu[(size_t)sA * 128 + lane];
    unsigned vA = kvu[(size_t)sA * 128 + 64 + lane];
    unsigned kB = kvu[(size_t)sB * 128 + lane];
    unsigned vB = kvu[(size_t)sB * 128 + 64 + lane];
    att_upd(kA, vA, qx, qy, d, ax, ay);
    att_upd(kB, vB, qx, qy, d, ax, ay);
    i += 2;
  }
  if (i < s1) {
    int sA = csr[i];
    unsigned kA = kvu[(size_t)sA * 128 + lane];
    unsigned vA = kvu[(size_t)sA * 128 + 64 + lane];
    att_upd(kA, vA, qx, qy, d, ax, ay);
  }
  if (d > 0.f) { float inv = 1.f / d; ax *= inv; ay *= inv; }
  float2 sv = *(const float2*)&sf[(size_t)wid * 128 + gc];
  float bl = ax * Wbeta[gc] + ay * Wbeta[gc + 1]
           + sv.x * Wbeta[128 + gc] + sv.y * Wbeta[129 + gc]
           + (ax - sv.x) * Wbeta[256 + gc] + (ay - sv.y) * Wbeta[257 + gc];
  bl += __shfl_xor(bl, 1);  bl += __shfl_xor(bl, 2);  bl += __shfl_xor(bl, 4);
  bl += __shfl_xor(bl, 8);  bl += __shfl_xor(bl, 16); bl += __shfl_xor(bl, 32);
  float beta = 1.f / (1.f + __expf(-bl));
  float hx = beta * sv.x + (1.f - beta) * ax;
  float hy = beta * sv.y + (1.f - beta) * ay;
  float s = hx + hy, sq = hx * hx + hy * hy;
  s += __shfl_xor(s, 1);  sq += __shfl_xor(sq, 1);
  s += __shfl_xor(s, 2);  sq += __shfl_xor(sq, 2);
  s += __shfl_xor(s, 4);  sq += __shfl_xor(sq, 4);
  s += __shfl_xor(s, 8);  sq += __shfl_xor(sq, 8);
  s += __shfl_xor(s, 16); sq += __shfl_xor(sq, 16);
  s += __shfl_xor(s, 32); sq += __shfl_xor(sq, 32);
  float mu = s * (1.f / 128.f);
  float var = sq * (1.f / 128.f) - mu * mu;
  float rstd = 1.f / sqrtf(var + 1e-5f);
  float y0 = (hx - mu) * rstd * lng[gc] + lnb[gc];
  float y1 = (hy - mu) * rstd * lng[gc + 1] + lnb[gc + 1];
  y0 = 0.5f * y0 * (1.f + erff(y0 * 0.70710678118654752f));
  y1 = 0.5f * y1 * (1.f + erff(y1 * 0.70710678118654752f));
  *(float2*)&hout[(size_t)wid * 128 + gc] = make_float2(y0, y1);
}

// ---------------- mean pool ----------------
__global__ __launch_bounds__(256) void pool_kernel(const float* __restrict__ h,
    const int* __restrict__ batch, float* __restrict__ g,
    float* __restrict__ gcnt, int N) {
  __shared__ float accS[NG * HIDD];
  __shared__ float cntS[NG];
  int t = threadIdx.x;
  for (int i = t; i < NG * HIDD; i += 256) accS[i] = 0.f;
  if (t < NG) cntS[t] = 0.f;
  __syncthreads();
  int lane = t & 63, grp = t >> 6;
  for (int n = blockIdx.x * 4 + grp; n < N; n += gridDim.x * 4) {
    int b = batch[n];
    float2 hv = *(const float2*)&h[(size_t)n * HIDD + (lane << 1)];
    atomicAdd(&accS[b * HIDD + (lane << 1)], hv.x);
    atomicAdd(&accS[b * HIDD + (lane << 1) + 1], hv.y);
    if (lane == 0) atomicAdd(&cntS[b], 1.f);
  }
  __syncthreads();
  for (int i = t; i < NG * HIDD; i += 256)
    if (accS[i] != 0.f) atomicAdd(&g[i], accS[i]);
  if (t < NG && cntS[t] != 0.f) atomicAdd(&gcnt[t], cntS[t]);
}

// ---------------- final MLP (single block) ----------------
__global__ __launch_bounds__(256) void final_kernel(const float* __restrict__ g,
    const float* __restrict__ gcnt, const float* __restrict__ W1,
    const float* __restrict__ b1, const float* __restrict__ W2,
    const float* __restrict__ b2, float* __restrict__ out) {
  __shared__ float gS[NG * HIDD];
  __shared__ float hmS[NG * HIDD];
  int t = threadIdx.x;
  for (int i = t; i < NG * HIDD; i += 256) {
    int gr = i >> 7;
    gS[i] = g[i] / fmaxf(gcnt[gr], 1.f);
  }
  __syncthreads();
  for (int i = t; i < NG * HIDD; i += 256) {
    int gr = i >> 7, col = i & 127;
    float s = b1[col];
    for (int k = 0; k < HIDD; ++k) s = fmaf(gS[gr * HIDD + k], W1[k * HIDD + col], s);
    hmS[i] = 0.5f * s * (1.f + erff(s * 0.70710678118654752f));
  }
  __syncthreads();
  if (t < NG) {
    float s = b2[0];
    for (int k = 0; k < HIDD; ++k) s = fmaf(hmS[t * HIDD + k], W2[k], s);
    out[t] = s;
  }
}

extern "C" void kernel_launch(void* const* d_in, const int* in_sizes, int n_in,
                              void* d_out, int out_size, void* d_ws, size_t ws_size,
                              hipStream_t stream) {
  const float* x        = (const float*)d_in[0];
  const int*   ei       = (const int*)d_in[1];
  const int*   batch    = (const int*)d_in[2];
  const float* l0_Wq    = (const float*)d_in[3];
  const float* l0_bq    = (const float*)d_in[4];
  const float* l0_Wk    = (const float*)d_in[5];
  const float* l0_bk    = (const float*)d_in[6];
  const float* l0_Wv    = (const float*)d_in[7];
  const float* l0_bv    = (const float*)d_in[8];
  const float* l0_Ws    = (const float*)d_in[9];
  const float* l0_bs    = (const float*)d_in[10];
  const float* l0_Wbeta = (const float*)d_in[11];
  const float* l0_lng   = (const float*)d_in[12];
  const float* l0_lnb   = (const float*)d_in[13];
  const float* Wq       = (const float*)d_in[14];
  const float* bq       = (const float*)d_in[15];
  const float* Wk       = (const float*)d_in[16];
  const float* bk       = (const float*)d_in[17];
  const float* Wv       = (const float*)d_in[18];
  const float* bv       = (const float*)d_in[19];
  const float* Ws       = (const float*)d_in[20];
  const float* bs       = (const float*)d_in[21];
  const float* Wbeta    = (const float*)d_in[22];
  const float* lng      = (const float*)d_in[23];
  const float* lnb      = (const float*)d_in[24];
  const float* mlp_W1   = (const float*)d_in[25];
  const float* mlp_b1   = (const float*)d_in[26];
  const float* mlp_W2   = (const float*)d_in[27];
  const float* mlp_b2   = (const float*)d_in[28];
  float* outp = (float*)d_out;

  char* ws = (char*)d_ws;
  size_t off = 0;
  auto alloc = [&](size_t bytes) -> void* {
    void* p = ws + off;
    off = (off + bytes + 255) & ~(size_t)255;
    return p;
  };
  float*  h0     = (float*)alloc((size_t)NN * HIDD * 4);
  float*  h1     = (float*)alloc((size_t)NN * HIDD * 4);
  float*  qf     = (float*)alloc((size_t)NN * HIDD * 4);
  float*  sf     = (float*)alloc((size_t)NN * HIDD * 4);
  unsigned short* kvb = (unsigned short*)alloc((size_t)NN * 256 * 2);
  short*  wT     = (short*)alloc((size_t)163840 * 2);
  int*    starts = (int*)alloc((size_t)(NN + 1) * 4);
  int*    pos    = (int*)alloc((size_t)NN * 4);
  int*    csr    = (int*)alloc((size_t)EE * 4);
  int*    btot   = (int*)alloc((size_t)NB1 * 4);
  int*    boff   = (int*)alloc((size_t)NB1 * 4);
  float*  g      = (float*)alloc((size_t)NG * HIDD * 4);
  float*  gcnt   = (float*)alloc((size_t)NG * 4);
  (void)ws_size; (void)in_sizes; (void)n_in; (void)out_size;

  // ---- weight prep (transpose + bf16 cast) ----
  PrepW pw = {{l0_Wq, l0_Wk, l0_Wv, l0_Ws,
               Wq, Wk, Wv, Ws,
               Wq + 16384, Wk + 16384, Wv + 16384, Ws + 16384}};
  prep_kernel<<<640, 256, 0, stream>>>(pw, wT);

  // ---- CSR build (by dst) ----
  hipMemsetAsync(pos, 0, (size_t)NN * 4, stream);
  count_kernel<<<(EE + 255) / 256, 256, 0, stream>>>(ei, pos, EE);
  scan1_kernel<<<NB1, 1024, 0, stream>>>(pos, starts, btot);
  scan2_kernel<<<1, 64, 0, stream>>>(btot, boff, starts);
  scan3_kernel<<<(NN + 255) / 256, 256, 0, stream>>>(starts, boff, pos);
  scatter_kernel<<<(EE + 255) / 256, 256, 0, stream>>>(ei, pos, csr, EE);

  int ggrid = (NN + 63) / 64;
  int agrid = (NN + 3) / 4;
  const unsigned* kvu = (const unsigned*)kvb;

  // ---- layer 0 (64 -> 128) ----
  BiasW b0 = {{l0_bq, l0_bk, l0_bv, l0_bs}};
  gemm_qkvs<DIN><<<ggrid, 256, 0, stream>>>(x, wT, b0, qf, kvb, sf, NN);
  attn_fused<<<agrid, 256, 0, stream>>>(qf, kvu, sf, starts, csr, l0_Wbeta,
                                        l0_lng, l0_lnb, h0, NN);

  // ---- layer 1 ----
  BiasW b1s = {{bq, bk, bv, bs}};
  gemm_qkvs<HIDD><<<ggrid, 256, 0, stream>>>(h0, wT + 32768, b1s, qf, kvb, sf, NN);
  attn_fused<<<agrid, 256, 0, stream>>>(qf, kvu, sf, starts, csr, Wbeta,
                                        lng, lnb, h1, NN);

  // ---- layer 2 ----
  BiasW b2s = {{bq + HIDD, bk + HIDD, bv + HIDD, bs + HIDD}};
  gemm_qkvs<HIDD><<<ggrid, 256, 0, stream>>>(h1, wT + 98304, b2s, qf, kvb, sf, NN);
  attn_fused<<<agrid, 256, 0, stream>>>(qf, kvu, sf, starts, csr, Wbeta + 384,
                                        lng + HIDD, lnb + HIDD, h0, NN);

  // ---- pool + MLP ----
  hipMemsetAsync(g, 0, (size_t)NG * HIDD * 4, stream);
  hipMemsetAsync(gcnt, 0, (size_t)NG * 4, stream);
  pool_kernel<<<256, 256, 0, stream>>>(h0, batch, g, gcnt, NN);
  final_kernel<<<1, 256, 0, stream>>>(g, gcnt, mlp_W1, mlp_b1, mlp_W2, mlp_b2, outp);
}